// Round 7
// baseline (158.807 us; speedup 1.0000x reference)
//
#include <hip/hip_runtime.h>
#include <hip/hip_bf16.h>

typedef __attribute__((ext_vector_type(8))) short short8;
typedef __attribute__((ext_vector_type(4))) float floatx4;

#define L2E 1.4426950408889634f

#if __has_builtin(__builtin_amdgcn_exp2f)
#define EXP2(x) __builtin_amdgcn_exp2f(x)
#else
#define EXP2(x) exp2f(x)
#endif
#if __has_builtin(__builtin_amdgcn_rcpf)
#define RCP(x) __builtin_amdgcn_rcpf(x)
#else
#define RCP(x) (1.0f / (x))
#endif

static __device__ __forceinline__ unsigned short f2bf(float f) {
    unsigned int u = __builtin_bit_cast(unsigned int, f);
    u += 0x7fffu + ((u >> 16) & 1u);   // RNE
    return (unsigned short)(u >> 16);
}
static __device__ __forceinline__ unsigned int pk_bf16(float a, float b) {
    __hip_bfloat162 h2 = __float22bfloat162_rn(make_float2(a, b));   // v_cvt_pk_bf16_f32
    unsigned int u;
    __builtin_memcpy(&u, &h2, 4);     // low16 = a, high16 = b
    return u;
}

// ---------------- 1) QKV GEMM, self-staging (unchanged) ----------------
__global__ __launch_bounds__(256) void k_qkv(const float* __restrict__ x,
                                             const float* __restrict__ qw,
                                             unsigned short* __restrict__ qm,
                                             unsigned short* __restrict__ km,
                                             unsigned short* __restrict__ vt) {
    __shared__ __align__(16) unsigned short At[64][136];
    __shared__ __align__(16) unsigned short Wt[64][136];
    const int tid = threadIdx.x;
    const int wave = tid >> 6, lane = tid & 63;
    const int l16 = lane & 15, quad = lane >> 4;
    const int m0 = blockIdx.x * 64;
    const int o0 = blockIdx.y * 64;

    floatx4 acc[4] = {};
    for (int rnd = 0; rnd < 2; ++rnd) {
        const int cbase = rnd * 128;
        if (rnd) __syncthreads();
        {
            const int moff = (tid & 3) * 16;
            #pragma unroll
            for (int half = 0; half < 2; ++half) {
                const int c_l = (tid >> 2) + 64 * half;
                const float4* xp = reinterpret_cast<const float4*>(
                    x + (size_t)(cbase + c_l) * 4096 + m0 + moff);
                const float4 f0 = xp[0], f1 = xp[1], f2 = xp[2], f3 = xp[3];
                At[moff +  0][c_l] = f2bf(f0.x); At[moff +  1][c_l] = f2bf(f0.y);
                At[moff +  2][c_l] = f2bf(f0.z); At[moff +  3][c_l] = f2bf(f0.w);
                At[moff +  4][c_l] = f2bf(f1.x); At[moff +  5][c_l] = f2bf(f1.y);
                At[moff +  6][c_l] = f2bf(f1.z); At[moff +  7][c_l] = f2bf(f1.w);
                At[moff +  8][c_l] = f2bf(f2.x); At[moff +  9][c_l] = f2bf(f2.y);
                At[moff + 10][c_l] = f2bf(f2.z); At[moff + 11][c_l] = f2bf(f2.w);
                At[moff + 12][c_l] = f2bf(f3.x); At[moff + 13][c_l] = f2bf(f3.y);
                At[moff + 14][c_l] = f2bf(f3.z); At[moff + 15][c_l] = f2bf(f3.w);
            }
        }
        {
            const int o_l = tid >> 2, cp = (tid & 3) * 32;
            const float4* wp = reinterpret_cast<const float4*>(
                qw + (size_t)(o0 + o_l) * 256 + cbase + cp);
            #pragma unroll
            for (int j = 0; j < 2; ++j) {
                const float4 g0 = wp[4 * j + 0], g1 = wp[4 * j + 1];
                const float4 g2 = wp[4 * j + 2], g3 = wp[4 * j + 3];
                unsigned int u[8];
                u[0] = pk_bf16(g0.x, g0.y); u[1] = pk_bf16(g0.z, g0.w);
                u[2] = pk_bf16(g1.x, g1.y); u[3] = pk_bf16(g1.z, g1.w);
                u[4] = pk_bf16(g2.x, g2.y); u[5] = pk_bf16(g2.z, g2.w);
                u[6] = pk_bf16(g3.x, g3.y); u[7] = pk_bf16(g3.z, g3.w);
                __builtin_memcpy(&Wt[o_l][cp + 16 * j], u, 32);
            }
        }
        __syncthreads();
        #pragma unroll
        for (int cc = 0; cc < 4; ++cc) {
            const int c0 = cc * 32 + quad * 8;
            const short8 a = *reinterpret_cast<const short8*>(&At[wave * 16 + l16][c0]);
            #pragma unroll
            for (int t4 = 0; t4 < 4; ++t4) {
                const short8 b = *reinterpret_cast<const short8*>(&Wt[t4 * 16 + l16][c0]);
                acc[t4] = __builtin_amdgcn_mfma_f32_16x16x32_bf16(a, b, acc[t4], 0, 0, 0);
            }
        }
    }
    const float qscale = 0.17677669529663687f * L2E;
    #pragma unroll
    for (int t4 = 0; t4 < 4; ++t4) {
        #pragma unroll
        for (int r = 0; r < 4; ++r) {
            const int n = m0 + wave * 16 + quad * 4 + r;
            const int o = o0 + t4 * 16 + l16;
            const int s = o >> 8, rem = o & 255, head = rem >> 5, t = rem & 31;
            if (s == 0)       qm[((size_t)head * 4096 + n) * 32 + t] = f2bf(acc[t4][r] * qscale);
            else if (s == 1)  km[((size_t)head * 4096 + n) * 32 + t] = f2bf(acc[t4][r]);
            else              vt[((size_t)head * 32 + t) * 4096 + n] = f2bf(acc[t4][r]);
        }
    }
}

// ---------------- 2) flash attention: LDS K/V + in-register P^T (ds_bpermute) ----------------
// R22 == R21 resubmitted (R21 bench was an infra failure, no data). R20's
// permlane-swap transpose failed numerically (ambiguous swap-direction
// semantics); this uses ds_bpermute_b32 (pull: dst[lane]=src[addr>>2] --
// unambiguous). PV B-operand at lane (quad,l16), dword d = keys
// kt*32+quad*8+2d,+2d+1: local key l=(quad&1)*8+2d is even -> pair comes from
// u0 (d even) or u1 (d odd) at source lane 2(quad&1)*16+l16 (d<2) or +16 (d>=2);
// subtile A if quad<2 else B. 16 independent bpermutes (one lgkm wait) + 8
// cndmasks per tile replace the PT LDS round-trip (8 ds_write + wait + 4
// conflicted b128 reads, ~240cy serial; 3.4M bank conflicts) and free 9.2KB LDS.
__global__ __launch_bounds__(256, 2) void k_attn(const unsigned short* __restrict__ qm,
                                                 const unsigned short* __restrict__ km,
                                                 const unsigned short* __restrict__ vt,
                                                 unsigned short* __restrict__ ao) {
    const int h   = blockIdx.y;
    const int nq0 = blockIdx.x * 64;          // 64 q-rows per block (same dq for all)
    const int tid = threadIdx.x;
    const int wv  = tid >> 6;                 // wave owns q-tile nq0 + wv*16
    const int lane = tid & 63;
    const int l16 = lane & 15, quad = lane >> 4;
    const int nqw = nq0 + wv * 16;

    __shared__ __align__(16) unsigned short Kt[2][2048];   // [buf][key*32+dim ^ swz]
    __shared__ __align__(16) unsigned short Vt[2][2048];   // [buf][kg*256+dim*8 ^ swz]

    // B-operand for S^T: Q^T (q on l16, k=c on quad*8+j)
    const short8 a_q = *reinterpret_cast<const short8*>(
        qm + ((size_t)h * 4096 + nqw + l16) * 32 + quad * 8);

    const int hq = (nqw >> 4) & 15;           // per-wave h-coordinate
    const int dq = nq0 >> 8;                  // block-uniform d-coordinate
    float dw2[4];
    #pragma unroll
    for (int r = 0; r < 4; ++r) {
        const float dw = (float)(quad * 4 + r - l16);   // key_w - q_w
        dw2[r] = dw * dw;
    }

    const int dk_lo = (dq > 9) ? dq - 9 : 0;
    const int dk_hi = (dq < 6) ? dq + 9 : 15;
    const int NT = 4 * (dk_hi - dk_lo + 1);   // 40..64 tiles, all waves do all tiles

    // staging roles (256 threads move one 4KB K-tile + 4KB V-tile)
    const int skey = tid >> 2;                // K: key 0..63
    const int sdo  = (tid & 3) * 8;           //    dim offset 0/8/16/24
    const int sdim = tid >> 3;                // V: dim 0..31
    const int skg  = tid & 7;                 //    keygroup 0..7
    const unsigned short* ksrc = km + ((size_t)h << 17) + skey * 32 + sdo;
    const unsigned short* vsrc = vt + (((size_t)h * 32 + sdim) << 12) + skg * 8;
    const int kdst = (skey * 32 + sdo) ^ ((skey & 7) << 3);
    const int vdst = (skg * 256 + sdim * 8) ^ (skg << 3);

    // bpermute pull addresses (bytes = src_lane*4), loop-invariant
    const int blo = ((quad & 1) << 7) + (l16 << 2);   // lane 2(quad&1)*16 + l16
    const int bhi = blo + 64;                         // +16 lanes
    const bool selA = (quad < 2);

    float l_acc = 0.f;
    floatx4 o_acc[2] = {};

#define J0T(T) (((dk_lo + ((T) >> 2)) << 8) + (((T) & 3) << 6))

    // ---- prologue: tile 0 -> buf 0; tile 1 -> regs ----
    short8 gK, gV;
    {
        const int j0 = J0T(0);
        gK = *reinterpret_cast<const short8*>(ksrc + (size_t)j0 * 32);
        gV = *reinterpret_cast<const short8*>(vsrc + j0);
        *reinterpret_cast<short8*>(&Kt[0][kdst]) = gK;
        *reinterpret_cast<short8*>(&Vt[0][vdst]) = gV;
        const int j1 = J0T(1);
        gK = *reinterpret_cast<const short8*>(ksrc + (size_t)j1 * 32);
        gV = *reinterpret_cast<const short8*>(vsrc + j1);
    }
    __syncthreads();

    for (int t = 0; t < NT; ++t) {
        const int cb = t & 1, nb = cb ^ 1;

        // (A) write tile t+1 (held in regs) into the other buffer
        *reinterpret_cast<short8*>(&Kt[nb][kdst]) = gK;
        *reinterpret_cast<short8*>(&Vt[nb][vdst]) = gV;

        // (B) prefetch tile t+2 into regs (clamped; load->use = one full iteration)
        {
            const int tn = (t + 2 < NT) ? t + 2 : NT - 1;
            const int j2 = J0T(tn);
            gK = *reinterpret_cast<const short8*>(ksrc + (size_t)j2 * 32);
            gV = *reinterpret_cast<const short8*>(vsrc + j2);
        }

        // (C) per-wave compute on tile t from buf cb
        {
            const int dk = dk_lo + (t >> 2), g = t & 3;
            const int dd = dq - dk;
            const int bb = 100 - dd * dd;
            const int h0 = hq - 4 * g;
            int thr[4];
            thr[0] = bb - h0 * h0;
            thr[1] = bb - (h0 - 1) * (h0 - 1);
            thr[2] = bb - (h0 - 2) * (h0 - 2);
            thr[3] = bb - (h0 - 3) * (h0 - 3);

            if (thr[0] > 0 || thr[1] > 0 || thr[2] > 0 || thr[3] > 0) {
                // S stage: K frags from LDS, MFMA, exp, pack P in registers.
                // u0[t4] = pk(P[key=16t4+4q+0][l16], P[key=16t4+4q+1][l16])
                // u1[t4] = pk(P[key=16t4+4q+2][l16], P[key=16t4+4q+3][l16])
                unsigned int u0[4], u1[4];
                #pragma unroll
                for (int t4 = 0; t4 < 4; ++t4) {
                    if (thr[t4] > 0) {
                        const short8 kf = *reinterpret_cast<const short8*>(
                            &Kt[cb][((t4 * 16 + l16) * 32 + quad * 8) ^ ((l16 & 7) << 3)]);
                        const floatx4 sf = __builtin_amdgcn_mfma_f32_16x16x32_bf16(
                            kf, a_q, (floatx4){0.f, 0.f, 0.f, 0.f}, 0, 0, 0);
                        const float thrf = (float)thr[t4];
                        const float p0 = (dw2[0] < thrf) ? EXP2(sf[0]) : 0.f;
                        const float p1 = (dw2[1] < thrf) ? EXP2(sf[1]) : 0.f;
                        const float p2 = (dw2[2] < thrf) ? EXP2(sf[2]) : 0.f;
                        const float p3 = (dw2[3] < thrf) ? EXP2(sf[3]) : 0.f;
                        l_acc += (p0 + p1) + (p2 + p3);
                        u0[t4] = pk_bf16(p0, p1);
                        u1[t4] = pk_bf16(p2, p3);
                    } else {
                        u0[t4] = 0u;
                        u1[t4] = 0u;
                    }
                }
                // PV: B-operand built in-register via bpermute pull transpose.
                // target lane (qt,l16), dword d holds keys kt*32 + 8qt + 2d, +2d+1.
                #pragma unroll
                for (int kt = 0; kt < 2; ++kt) {
                    if (thr[2 * kt] > 0 || thr[2 * kt + 1] > 0) {
                        const int iA = 2 * kt, iB = 2 * kt + 1;
                        const int d0a = __builtin_amdgcn_ds_bpermute(blo, (int)u0[iA]);
                        const int d0b = __builtin_amdgcn_ds_bpermute(blo, (int)u0[iB]);
                        const int d1a = __builtin_amdgcn_ds_bpermute(blo, (int)u1[iA]);
                        const int d1b = __builtin_amdgcn_ds_bpermute(blo, (int)u1[iB]);
                        const int d2a = __builtin_amdgcn_ds_bpermute(bhi, (int)u0[iA]);
                        const int d2b = __builtin_amdgcn_ds_bpermute(bhi, (int)u0[iB]);
                        const int d3a = __builtin_amdgcn_ds_bpermute(bhi, (int)u1[iA]);
                        const int d3b = __builtin_amdgcn_ds_bpermute(bhi, (int)u1[iB]);
                        unsigned int bw[4];
                        bw[0] = (unsigned int)(selA ? d0a : d0b);
                        bw[1] = (unsigned int)(selA ? d1a : d1b);
                        bw[2] = (unsigned int)(selA ? d2a : d2b);
                        bw[3] = (unsigned int)(selA ? d3a : d3b);
                        short8 b_p;
                        __builtin_memcpy(&b_p, bw, 16);
                        const int kg = kt * 4 + quad;
                        #pragma unroll
                        for (int hf = 0; hf < 2; ++hf) {
                            const short8 vf = *reinterpret_cast<const short8*>(
                                &Vt[cb][(kg * 256 + (hf * 16 + l16) * 8) ^ (kg << 3)]);
                            o_acc[hf] = __builtin_amdgcn_mfma_f32_16x16x32_bf16(
                                vf, b_p, o_acc[hf], 0, 0, 0);
                        }
                    }
                }
            }
        }
        __syncthreads();
    }
#undef J0T

    // ---- epilogue: waves own disjoint q-rows; direct write ----
    l_acc += __shfl_xor(l_acc, 16);
    l_acc += __shfl_xor(l_acc, 32);
    const float inv = RCP(l_acc);
    #pragma unroll
    for (int hf = 0; hf < 2; ++hf) {
        unsigned int uu[2];
        uu[0] = pk_bf16(o_acc[hf][0] * inv, o_acc[hf][1] * inv);
        uu[1] = pk_bf16(o_acc[hf][2] * inv, o_acc[hf][3] * inv);
        __builtin_memcpy(ao + (size_t)(nqw + l16) * 256 + h * 32 + hf * 16 + quad * 4,
                         uu, 8);
    }
}

// ---------------- 3) proj GEMM + bias, self-staging pw (unchanged) ----------------
__global__ __launch_bounds__(256) void k_proj(const unsigned short* __restrict__ ao,
                                              const float* __restrict__ pw,
                                              const float* __restrict__ pb,
                                              float* __restrict__ out) {
    __shared__ __align__(16) unsigned short Pt[64][264];
    const int tid = threadIdx.x;
    const int wave = tid >> 6, lane = tid & 63;
    const int l16 = lane & 15, quad = lane >> 4;
    const int n0 = blockIdx.x * 64;
    const int m0 = blockIdx.y * 64;

    {
        const int o_l = tid >> 2, cp = (tid & 3) * 64;
        const float4* wp = reinterpret_cast<const float4*>(pw + (size_t)(m0 + o_l) * 256 + cp);
        #pragma unroll
        for (int j = 0; j < 4; ++j) {
            const float4 g0 = wp[4 * j + 0], g1 = wp[4 * j + 1];
            const float4 g2 = wp[4 * j + 2], g3 = wp[4 * j + 3];
            unsigned int u[8];
            u[0] = pk_bf16(g0.x, g0.y); u[1] = pk_bf16(g0.z, g0.w);
            u[2] = pk_bf16(g1.x, g1.y); u[3] = pk_bf16(g1.z, g1.w);
            u[4] = pk_bf16(g2.x, g2.y); u[5] = pk_bf16(g2.z, g2.w);
            u[6] = pk_bf16(g3.x, g3.y); u[7] = pk_bf16(g3.z, g3.w);
            __builtin_memcpy(&Pt[o_l][cp + 16 * j], u, 32);
        }
    }
    __syncthreads();

    floatx4 acc[4] = {};
    #pragma unroll
    for (int cc = 0; cc < 8; ++cc) {
        const int c0 = cc * 32 + quad * 8;
        const short8 a = *reinterpret_cast<const short8*>(&Pt[wave * 16 + l16][c0]);
        #pragma unroll
        for (int t4 = 0; t4 < 4; ++t4) {
            const short8 b = *reinterpret_cast<const short8*>(
                ao + (size_t)(n0 + t4 * 16 + l16) * 256 + c0);
            acc[t4] = __builtin_amdgcn_mfma_f32_16x16x32_bf16(a, b, acc[t4], 0, 0, 0);
        }
    }
    #pragma unroll
    for (int t4 = 0; t4 < 4; ++t4) {
        #pragma unroll
        for (int r = 0; r < 4; ++r) {
            const int o = m0 + wave * 16 + quad * 4 + r;
            const int n = n0 + t4 * 16 + l16;
            out[(size_t)o * 4096 + n] = acc[t4][r] + pb[o];
        }
    }
}

extern "C" void kernel_launch(void* const* d_in, const int* in_sizes, int n_in,
                              void* d_out, int out_size, void* d_ws, size_t ws_size,
                              hipStream_t stream) {
    const float* x      = (const float*)d_in[0];
    const float* qkv_w  = (const float*)d_in[1];
    const float* proj_w = (const float*)d_in[2];
    const float* proj_b = (const float*)d_in[3];
    float* out = (float*)d_out;                    // [256,4096] fp32

    char* B = (char*)d_ws;
    const size_t MB = 1u << 20;
    unsigned short* ao = (unsigned short*)(B);
    unsigned short* qm = (unsigned short*)(B + 2 * MB);
    unsigned short* km = (unsigned short*)(B + 4 * MB);
    unsigned short* vt = (unsigned short*)(B + 6 * MB);

    k_qkv<<<dim3(64, 12), 256, 0, stream>>>(x, qkv_w, qm, km, vt);
    k_attn<<<dim3(64, 8), 256, 0, stream>>>(qm, km, vt, ao);
    k_proj<<<dim3(64, 4), 256, 0, stream>>>(ao, proj_w, proj_b, out);
}